// Round 1
// 5043.655 us; speedup vs baseline: 1.1869x; 1.1869x over previous
//
#include <hip/hip_runtime.h>
#include <math.h>

#define NTHR   512
#define SWEEPS 7

// Ring movement (round-robin / Brent-Luk): content of slot s moves to next(s).
// slot 0 fixed; even s -> s+2 (62 -> 63); odd s -> s-2 (1 -> 2).
__device__ __forceinline__ int ring_next_even(int s) {   // s even
    return (s == 0) ? 0 : ((s == 62) ? 63 : s + 2);
}
__device__ __forceinline__ int ring_next_odd(int s) {    // s odd
    return (s == 1) ? 2 : s - 2;
}
// Split-parity column position: even cols -> 0..31, odd cols -> 32..63.
// Makes the 32 same-parity column accesses of one instr hit 32 distinct banks.
__device__ __forceinline__ int cpos(int c) {
    return (c >> 1) + ((c & 1) << 5);
}

// 512 threads/block (8 waves), same 32.5 KB LDS per matrix as before:
// 4 blocks/CU * 8 waves = 32 waves/CU = 100% occupancy (was 16 waves, 46%).
// __launch_bounds__(512, 8): 8 waves/EU -> VGPR capped at 64 (was 52).
__global__ __launch_bounds__(NTHR, 8)
void logeig_jacobi(const float* __restrict__ x, float* __restrict__ out) {
    __shared__ float A[64 * 64];    // rows x split-parity column positions
    __shared__ float Vt[64 * 64];   // plain row-major (rows move, cols never)
    __shared__ __align__(16) float2 prm[32];
    __shared__ float logw[64];

    const int tid = threadIdx.x;
    const int w   = tid >> 6;              // wave id 0..7
    const int lan = tid & 63;
    const int J   = tid & 31;              // column-pair id
    const int bit = (lan >> 5) & 1;
    const int base = 4 * w + bit;          // row-pair I = base + 2k, k<2
    const int kv  = tid >> 4;              // Vt row-pair id 0..31
    const int cch = tid & 15;              // Vt float4 chunk

    // thread-constant A write column positions (after ring move)
    const int wpP = cpos(ring_next_even(2 * J));
    const int wpQ = cpos(ring_next_odd(2 * J + 1));

    const size_t base_el = (size_t)blockIdx.x * 4096;

    // ---- load A into split-parity layout (float4 -> two float2), Vt = I ----
    {
        const float4* x4 = (const float4*)(x + base_el);
        for (int idx4 = tid; idx4 < 1024; idx4 += NTHR) {
            int i = idx4 >> 4, t = idx4 & 15;      // cols 4t..4t+3
            float4 v = x4[idx4];
            // evens 4t,4t+2 -> pos 2t,2t+1 ; odds -> pos 32+2t, 32+2t+1
            *(float2*)&A[i * 64 + 2 * t]      = make_float2(v.x, v.z);
            *(float2*)&A[i * 64 + 32 + 2 * t] = make_float2(v.y, v.w);
            float4 id;
            id.x = (4 * t + 0 == i) ? 1.0f : 0.0f;
            id.y = (4 * t + 1 == i) ? 1.0f : 0.0f;
            id.z = (4 * t + 2 == i) ? 1.0f : 0.0f;
            id.w = (4 * t + 3 == i) ? 1.0f : 0.0f;
            ((float4*)Vt)[idx4] = id;
        }
    }
    __syncthreads();

    for (int sweep = 0; sweep < SWEEPS; ++sweep) {
        for (int r = 0; r < 63; ++r) {
            // ---- rotation params for the 32 adjacent slot pairs ----
            if (tid < 32) {
                int k = tid;
                float app = A[(2 * k) * 64 + k];            // pos(2k)   = k
                float apq = A[(2 * k) * 64 + k + 32];       // pos(2k+1) = k+32
                float aqq = A[(2 * k + 1) * 64 + k + 32];
                float c = 1.0f, s = 0.0f;
                if (apq != 0.0f) {
                    float tau = (aqq - app) / (2.0f * apq);
                    float t   = copysignf(1.0f, tau) /
                                (fabsf(tau) + sqrtf(1.0f + tau * tau));
                    c = 1.0f / sqrtf(1.0f + t * t);
                    s = t * c;
                }
                prm[k] = make_float2(c, s);
            }

            // ---- read old A 2x2 blocks (conflict-free b32 pairs) and Vt ----
            float4 ablk[2];
            #pragma unroll
            for (int k = 0; k < 2; ++k) {
                int r0 = (2 * (base + 2 * k)) * 64;
                int r1 = r0 + 64;
                ablk[k] = make_float4(A[r0 + J], A[r0 + J + 32],
                                      A[r1 + J], A[r1 + J + 32]);
            }
            // Vt: one row-pair per thread (16-lane contiguous float4 groups)
            float4 vtop = *(const float4*)&Vt[(2 * kv) * 64 + 4 * cch];
            float4 vbot = *(const float4*)&Vt[(2 * kv + 1) * 64 + 4 * cch];
            __syncthreads();   // B1: all reads done; prm visible

            float2 pJ = prm[J];
            float2 pV = prm[kv];           // 16-lane broadcast
            float2 pI[2];
            pI[0] = prm[base];
            pI[1] = prm[base + 2];

            // ---- rotate 2x2 blocks, write to ring-moved positions ----
            #pragma unroll
            for (int k = 0; k < 2; ++k) {
                float cI = pI[k].x, sI = pI[k].y;
                float cJ = pJ.x,   sJ = pJ.y;
                float m00 = ablk[k].x, m01 = ablk[k].y;
                float m10 = ablk[k].z, m11 = ablk[k].w;
                float t00 = cI * m00 - sI * m10, t01 = cI * m01 - sI * m11;
                float t10 = sI * m00 + cI * m10, t11 = sI * m01 + cI * m11;
                float n00 = cJ * t00 - sJ * t01, n01 = sJ * t00 + cJ * t01;
                float n10 = cJ * t10 - sJ * t11, n11 = sJ * t10 + cJ * t11;
                int I  = base + 2 * k;
                int dPr = ring_next_even(2 * I) * 64;
                int dQr = ring_next_odd(2 * I + 1) * 64;
                A[dPr + wpP] = n00;
                A[dPr + wpQ] = n01;
                A[dQr + wpP] = n10;
                A[dQr + wpQ] = n11;
            }

            // ---- rotate Vt row-pair, write to ring-moved rows ----
            {
                float cV = pV.x, sV = pV.y;
                int dPr = ring_next_even(2 * kv);
                int dQr = ring_next_odd(2 * kv + 1);
                float4 n0, n1;
                n0.x = cV * vtop.x - sV * vbot.x;  n1.x = sV * vtop.x + cV * vbot.x;
                n0.y = cV * vtop.y - sV * vbot.y;  n1.y = sV * vtop.y + cV * vbot.y;
                n0.z = cV * vtop.z - sV * vbot.z;  n1.z = sV * vtop.z + cV * vbot.z;
                n0.w = cV * vtop.w - sV * vbot.w;  n1.w = sV * vtop.w + cV * vbot.w;
                *(float4*)&Vt[dPr * 64 + 4 * cch] = n0;
                *(float4*)&Vt[dQr * 64 + 4 * cch] = n1;
            }
            __syncthreads();   // B2: writes done -> next round
        }
    }

    // ---- epilogue: out = Vt^T diag(log diag A) Vt ----
    if (tid < 64) {
        int p = (tid >> 1) + ((tid & 1) << 5);   // cpos(tid)
        logw[tid] = logf(A[tid * 64 + p]);
    }
    __syncthreads();

    // W[s][*] = Vt[s][*] * logw[s]  -> reuse A (plain layout now)
    for (int idx4 = tid; idx4 < 1024; idx4 += NTHR) {
        int k = idx4 >> 4;
        float lw = logw[k];
        float4 v = ((float4*)Vt)[idx4];
        v.x *= lw; v.y *= lw; v.z *= lw; v.w *= lw;
        ((float4*)A)[idx4] = v;
    }
    __syncthreads();

    // out[i][j] = sum_s W[s][i] * Vt[s][j]
    float4* out4 = (float4*)(out + base_el);
    for (int idx4 = tid; idx4 < 1024; idx4 += NTHR) {
        int i = idx4 >> 4, j4 = idx4 & 15;
        float4 acc = make_float4(0.0f, 0.0f, 0.0f, 0.0f);
        #pragma unroll 8
        for (int k = 0; k < 64; ++k) {
            float a = A[k * 64 + i];
            float4 vv = ((float4*)Vt)[k * 16 + j4];
            acc.x += a * vv.x; acc.y += a * vv.y;
            acc.z += a * vv.z; acc.w += a * vv.w;
        }
        out4[idx4] = acc;
    }
}

extern "C" void kernel_launch(void* const* d_in, const int* in_sizes, int n_in,
                              void* d_out, int out_size, void* d_ws, size_t ws_size,
                              hipStream_t stream) {
    const float* x = (const float*)d_in[0];
    float* o = (float*)d_out;
    int B = in_sizes[0] / 4096;   // 8192
    logeig_jacobi<<<B, NTHR, 0, stream>>>(x, o);
}